// Round 1
// baseline (856.895 us; speedup 1.0000x reference)
//
#include <hip/hip_runtime.h>

#define NN 100000   // nodes
#define NE 3200000  // edges
#define NF 512      // in features
#define NH 16       // hidden
#define NC 7        // classes
#define NPARTS ((NN + 255) / 256)   // 391 scan partials

// ---------------------------------------------------------------------------
// GEMM1: h0[n, 0:16] = x[n, 0:512] @ W1[512,16].  One wave per row.
// Each lane owns k in {4*lane..4*lane+3, 256+4*lane..256+4*lane+3}; W1 rows
// for those k live in registers (128 VGPRs), loaded once per wave.
// ---------------------------------------------------------------------------
__global__ __launch_bounds__(256) void gemm1_kernel(const float* __restrict__ x,
                                                    const float* __restrict__ W1,
                                                    float* __restrict__ h0) {
  const int lane = threadIdx.x & 63;
  const int wave = (blockIdx.x * blockDim.x + threadIdx.x) >> 6;
  const int nwaves = (gridDim.x * blockDim.x) >> 6;

  float w[8][NH];
#pragma unroll
  for (int i = 0; i < 4; ++i) {
#pragma unroll
    for (int j = 0; j < NH; ++j) {
      w[i][j]     = W1[(4 * lane + i) * NH + j];
      w[4 + i][j] = W1[(256 + 4 * lane + i) * NH + j];
    }
  }

  for (int row = wave; row < NN; row += nwaves) {
    const float4* xr = (const float4*)(x + (size_t)row * NF);
    float4 a0 = xr[lane];        // k = 4*lane .. 4*lane+3
    float4 a1 = xr[64 + lane];   // k = 256+4*lane ..
    float a[8] = {a0.x, a0.y, a0.z, a0.w, a1.x, a1.y, a1.z, a1.w};

    float acc[NH];
#pragma unroll
    for (int j = 0; j < NH; ++j) acc[j] = 0.f;
#pragma unroll
    for (int i = 0; i < 8; ++i) {
#pragma unroll
      for (int j = 0; j < NH; ++j) acc[j] += a[i] * w[i][j];
    }

    float outv = 0.f;
#pragma unroll
    for (int j = 0; j < NH; ++j) {
      float v = acc[j];
      v += __shfl_xor(v, 1);
      v += __shfl_xor(v, 2);
      v += __shfl_xor(v, 4);
      v += __shfl_xor(v, 8);
      v += __shfl_xor(v, 16);
      v += __shfl_xor(v, 32);
      if (lane == j) outv = v;   // lane j keeps column j's full sum
    }
    if (lane < NH) h0[(size_t)row * NH + lane] = outv;
  }
}

// ===========================================================================
// CSR build: histogram of in-degree -> exclusive scan -> fill sorted src list
// ===========================================================================
__global__ __launch_bounds__(256) void hist_kernel(const int* __restrict__ ei,
                                                   int* __restrict__ deg) {
  int e = blockIdx.x * 256 + threadIdx.x;
  if (e < NE) atomicAdd(&deg[ei[NE + e]], 1);
}

// Per-block (256-wide) exclusive scan of deg -> offs; block totals -> part.
__global__ __launch_bounds__(256) void scan1_kernel(const int* __restrict__ deg,
                                                    int* __restrict__ offs,
                                                    int* __restrict__ part) {
  __shared__ int sm[256];
  int tid = threadIdx.x;
  int i = blockIdx.x * 256 + tid;
  int v = (i < NN) ? deg[i] : 0;
  sm[tid] = v;
  __syncthreads();
  for (int off = 1; off < 256; off <<= 1) {
    int t = (tid >= off) ? sm[tid - off] : 0;
    __syncthreads();
    sm[tid] += t;
    __syncthreads();
  }
  if (i < NN) offs[i] = sm[tid] - v;               // exclusive
  if (tid == 255) part[blockIdx.x] = sm[255];      // block total
}

// Single-block exclusive scan of the NPARTS block totals.
__global__ __launch_bounds__(512) void scan2_kernel(int* __restrict__ part) {
  __shared__ int sm[512];
  int t = threadIdx.x;
  int v = (t < NPARTS) ? part[t] : 0;
  sm[t] = v;
  __syncthreads();
  for (int off = 1; off < 512; off <<= 1) {
    int u = (t >= off) ? sm[t - off] : 0;
    __syncthreads();
    sm[t] += u;
    __syncthreads();
  }
  if (t < NPARTS) part[t] = sm[t] - v;             // exclusive
}

// Add block bases; duplicate offsets into the fill cursors; cap with NE.
__global__ __launch_bounds__(256) void scan3_kernel(int* __restrict__ offs,
                                                    int* __restrict__ cur,
                                                    const int* __restrict__ part) {
  int i = blockIdx.x * 256 + threadIdx.x;
  if (i < NN) {
    int v = offs[i] + part[i >> 8];
    offs[i] = v;
    cur[i] = v;
  }
  if (i == 0) offs[NN] = NE;
}

// srcs[pos] = src, pos in dst's contiguous CSR slot range.
__global__ __launch_bounds__(256) void fill_kernel(const int* __restrict__ ei,
                                                   int* __restrict__ cur,
                                                   int* __restrict__ srcs) {
  int e = blockIdx.x * 256 + threadIdx.x;
  if (e < NE) {
    int s = ei[e];
    int d = ei[NE + e];
    int pos = atomicAdd(&cur[d], 1);
    srcs[pos] = s;
  }
}

// ===========================================================================
// Layer-1 aggregate (gather): one wave per node; lanes = 4 edge-slots x 16
// cols.  agg1[n, c] = sum over in-edges of h0[src, c].  No atomics.
// ===========================================================================
__global__ __launch_bounds__(256) void agg16_kernel(const int* __restrict__ offs,
                                                    const int* __restrict__ srcs,
                                                    const float* __restrict__ h0,
                                                    float* __restrict__ agg) {
  const int lane = threadIdx.x & 63;
  const int wave = (blockIdx.x * blockDim.x + threadIdx.x) >> 6;
  const int nw = (gridDim.x * blockDim.x) >> 6;
  const int col = lane & 15;
  const int slot = lane >> 4;   // 0..3

  for (int n = wave; n < NN; n += nw) {
    int beg = offs[n], end = offs[n + 1];
    float acc = 0.f;
    int e = beg + slot;
    for (; e + 4 < end; e += 8) {          // 2x unrolled, stride 4 per slot
      int s0 = srcs[e];
      int s1 = srcs[e + 4];
      acc += h0[(size_t)s0 * NH + col];
      acc += h0[(size_t)s1 * NH + col];
    }
    if (e < end) acc += h0[(size_t)srcs[e] * NH + col];
    acc += __shfl_xor(acc, 16);
    acc += __shfl_xor(acc, 32);
    if (lane < NH) agg[(size_t)n * NH + lane] = acc;
  }
}

// ---------------------------------------------------------------------------
// Per-node transform: p[n, 0:7] = relu(agg1[n] + b1) @ W2, p stride 8.
// ---------------------------------------------------------------------------
__global__ __launch_bounds__(256) void transform_kernel(const float* __restrict__ agg1,
                                                        const float* __restrict__ b1,
                                                        const float* __restrict__ W2,
                                                        float* __restrict__ p) {
  int n = blockIdx.x * blockDim.x + threadIdx.x;
  if (n >= NN) return;
  const float4* r = (const float4*)(agg1 + (size_t)n * NH);
  float4 v0 = r[0], v1 = r[1], v2 = r[2], v3 = r[3];
  float h[NH] = {v0.x, v0.y, v0.z, v0.w, v1.x, v1.y, v1.z, v1.w,
                 v2.x, v2.y, v2.z, v2.w, v3.x, v3.y, v3.z, v3.w};
#pragma unroll
  for (int k = 0; k < NH; ++k) h[k] = fmaxf(h[k] + b1[k], 0.f);

#pragma unroll
  for (int j = 0; j < NC; ++j) {
    float acc = 0.f;
#pragma unroll
    for (int k = 0; k < NH; ++k) acc += h[k] * W2[k * NC + j];
    p[(size_t)n * 8 + j] = acc;
  }
  p[(size_t)n * 8 + 7] = 0.f;   // keep pad lane clean for agg8
}

// ===========================================================================
// Layer-2 aggregate (gather): lanes = 8 edge-slots x 8 cols, p/agg2 stride 8.
// ===========================================================================
__global__ __launch_bounds__(256) void agg8_kernel(const int* __restrict__ offs,
                                                   const int* __restrict__ srcs,
                                                   const float* __restrict__ p,
                                                   float* __restrict__ agg) {
  const int lane = threadIdx.x & 63;
  const int wave = (blockIdx.x * blockDim.x + threadIdx.x) >> 6;
  const int nw = (gridDim.x * blockDim.x) >> 6;
  const int col = lane & 7;
  const int slot = lane >> 3;   // 0..7

  for (int n = wave; n < NN; n += nw) {
    int beg = offs[n], end = offs[n + 1];
    float acc = 0.f;
    int e = beg + slot;
    for (; e + 8 < end; e += 16) {         // 2x unrolled, stride 8 per slot
      int s0 = srcs[e];
      int s1 = srcs[e + 8];
      acc += p[(size_t)s0 * 8 + col];
      acc += p[(size_t)s1 * 8 + col];
    }
    if (e < end) acc += p[(size_t)srcs[e] * 8 + col];
    acc += __shfl_xor(acc, 8);
    acc += __shfl_xor(acc, 16);
    acc += __shfl_xor(acc, 32);
    if (lane < 8) agg[(size_t)n * 8 + lane] = acc;
  }
}

// ---------------------------------------------------------------------------
// log_softmax over 7 classes; agg2 stride 8 in, out stride 7.
// ---------------------------------------------------------------------------
__global__ __launch_bounds__(256) void lsm_kernel(const float* __restrict__ agg2,
                                                  const float* __restrict__ b2,
                                                  float* __restrict__ out) {
  int n = blockIdx.x * blockDim.x + threadIdx.x;
  if (n >= NN) return;
  float z[NC];
  float m = -1e30f;
#pragma unroll
  for (int j = 0; j < NC; ++j) {
    z[j] = agg2[(size_t)n * 8 + j] + b2[j];
    m = fmaxf(m, z[j]);
  }
  float s = 0.f;
#pragma unroll
  for (int j = 0; j < NC; ++j) s += __expf(z[j] - m);
  float l = __logf(s);
#pragma unroll
  for (int j = 0; j < NC; ++j) out[(size_t)n * NC + j] = z[j] - m - l;
}

// ===========================================================================
// Legacy atomic-scatter path (fallback when workspace is too small for CSR).
// ===========================================================================
__global__ __launch_bounds__(256) void scatter16_kernel(const int* __restrict__ ei,
                                                        const float* __restrict__ h0,
                                                        float* __restrict__ agg) {
  long long gid = (long long)blockIdx.x * blockDim.x + threadIdx.x;
  int e = (int)(gid >> 4);
  if (e >= NE) return;
  int j = (int)(gid & 15);
  int s = ei[e];
  int d = ei[NE + e];
  atomicAdd(&agg[(size_t)d * NH + j], h0[(size_t)s * NH + j]);
}

__global__ __launch_bounds__(256) void scatter7_kernel(const int* __restrict__ ei,
                                                       const float* __restrict__ p,
                                                       float* __restrict__ agg) {
  long long gid = (long long)blockIdx.x * blockDim.x + threadIdx.x;
  int e = (int)(gid >> 3);
  if (e >= NE) return;
  int j = (int)(gid & 7);
  if (j >= NC) return;
  int s = ei[e];
  int d = ei[NE + e];
  atomicAdd(&agg[(size_t)d * 8 + j], p[(size_t)s * 8 + j]);
}

extern "C" void kernel_launch(void* const* d_in, const int* in_sizes, int n_in,
                              void* d_out, int out_size, void* d_ws, size_t ws_size,
                              hipStream_t stream) {
  const float* x  = (const float*)d_in[0];
  const int*   ei = (const int*)d_in[1];   // [2, NE] int32: src row then dst row
  const float* W1 = (const float*)d_in[2];
  const float* b1 = (const float*)d_in[3];
  const float* W2 = (const float*)d_in[4];
  const float* b2 = (const float*)d_in[5];
  float* out = (float*)d_out;

  // CSR-path ws layout (26.4 MB):
  //   region1: h0[NN*16] (later reused as p[NN*8])
  //   region2: agg1[NN*16] (later reused as agg2[NN*8])
  //   offs[NN+1], cur[NN], part[512], srcs[NE]
  float* h0p  = (float*)d_ws;
  float* aggp = h0p + (size_t)NN * NH;
  int*   offs = (int*)(aggp + (size_t)NN * NH);
  int*   cur  = offs + (NN + 1);
  int*   part = cur + NN;
  int*   srcs = part + 512;
  size_t need = (size_t)((char*)(srcs + NE) - (char*)d_ws);

  if (ws_size >= need) {
    // ---- CSR gather path: no scatter atomics on the hot loop ----
    hipMemsetAsync(cur, 0, (size_t)NN * sizeof(int), stream);
    hist_kernel<<<(NE + 255) / 256, 256, 0, stream>>>(ei, cur);
    scan1_kernel<<<NPARTS, 256, 0, stream>>>(cur, offs, part);
    scan2_kernel<<<1, 512, 0, stream>>>(part);
    scan3_kernel<<<NPARTS, 256, 0, stream>>>(offs, cur, part);
    fill_kernel<<<(NE + 255) / 256, 256, 0, stream>>>(ei, cur, srcs);

    gemm1_kernel<<<2048, 256, 0, stream>>>(x, W1, h0p);
    agg16_kernel<<<2048, 256, 0, stream>>>(offs, srcs, h0p, aggp);
    transform_kernel<<<(NN + 255) / 256, 256, 0, stream>>>(aggp, b1, W2, h0p);
    agg8_kernel<<<2048, 256, 0, stream>>>(offs, srcs, h0p, aggp);
    lsm_kernel<<<(NN + 255) / 256, 256, 0, stream>>>(aggp, b2, out);
  } else {
    // ---- legacy path (12.8 MB ws): verified at 705 us ----
    float* bufA = (float*)d_ws;
    float* bufB = bufA + (size_t)NN * NH;

    hipMemsetAsync(bufB, 0, (size_t)NN * NH * sizeof(float), stream);
    gemm1_kernel<<<2048, 256, 0, stream>>>(x, W1, bufA);
    scatter16_kernel<<<(int)(((long long)NE * 16 + 255) / 256), 256, 0, stream>>>(ei, bufA, bufB);
    transform_kernel<<<(NN + 255) / 256, 256, 0, stream>>>(bufB, b1, W2, bufA);
    hipMemsetAsync(bufB, 0, (size_t)NN * 8 * sizeof(float), stream);
    scatter7_kernel<<<(int)(((long long)NE * 8 + 255) / 256), 256, 0, stream>>>(ei, bufA, bufB);
    lsm_kernel<<<(NN + 255) / 256, 256, 0, stream>>>(bufB, b2, out);
  }
}

// Round 2
// 832.213 us; speedup vs baseline: 1.0297x; 1.0297x over previous
//
#include <hip/hip_runtime.h>

#define NN 100000   // nodes
#define NE 3200000  // edges
#define NF 512      // in features
#define NH 16       // hidden
#define NC 7        // classes

#define NB   512            // dst buckets
#define SPAN 196            // nodes per bucket (512*196 = 100352 >= NN)
#define NBLK 256            // blocks for the edge-partition passes
#define EPB  (NE / NBLK)    // 12500 edges per block (exact)

// ---------------------------------------------------------------------------
// GEMM1: h0[n, 0:16] = x[n, 0:512] @ W1[512,16].  One wave per row.
// W1 rows for each lane's k-slice live in registers (128 VGPRs).
// ---------------------------------------------------------------------------
__global__ __launch_bounds__(256) void gemm1_kernel(const float* __restrict__ x,
                                                    const float* __restrict__ W1,
                                                    float* __restrict__ h0) {
  const int lane = threadIdx.x & 63;
  const int wave = (blockIdx.x * blockDim.x + threadIdx.x) >> 6;
  const int nwaves = (gridDim.x * blockDim.x) >> 6;

  float w[8][NH];
#pragma unroll
  for (int i = 0; i < 4; ++i) {
#pragma unroll
    for (int j = 0; j < NH; ++j) {
      w[i][j]     = W1[(4 * lane + i) * NH + j];
      w[4 + i][j] = W1[(256 + 4 * lane + i) * NH + j];
    }
  }

  for (int row = wave; row < NN; row += nwaves) {
    const float4* xr = (const float4*)(x + (size_t)row * NF);
    float4 a0 = xr[lane];
    float4 a1 = xr[64 + lane];
    float a[8] = {a0.x, a0.y, a0.z, a0.w, a1.x, a1.y, a1.z, a1.w};

    float acc[NH];
#pragma unroll
    for (int j = 0; j < NH; ++j) acc[j] = 0.f;
#pragma unroll
    for (int i = 0; i < 8; ++i) {
#pragma unroll
      for (int j = 0; j < NH; ++j) acc[j] += a[i] * w[i][j];
    }

    float outv = 0.f;
#pragma unroll
    for (int j = 0; j < NH; ++j) {
      float v = acc[j];
      v += __shfl_xor(v, 1);
      v += __shfl_xor(v, 2);
      v += __shfl_xor(v, 4);
      v += __shfl_xor(v, 8);
      v += __shfl_xor(v, 16);
      v += __shfl_xor(v, 32);
      if (lane == j) outv = v;
    }
    if (lane < NH) h0[(size_t)row * NH + lane] = outv;
  }
}

// ===========================================================================
// Bucket partition: edges -> dst-bucket-ordered packed records
//   record = src (bits 0..16) | dstLocal (bits 17..24), 4B each
// ===========================================================================
__global__ __launch_bounds__(512) void countK(const int* __restrict__ ei,
                                              int* __restrict__ bucketCount,
                                              int* __restrict__ blockBase) {
  __shared__ int cnt[NB];
  const int b = blockIdx.x, tid = threadIdx.x;
  cnt[tid] = 0;                      // blockDim == NB == 512
  __syncthreads();
  const int base = b * EPB;
  for (int e = tid; e < EPB; e += 512) {
    int d = ei[NE + base + e];
    atomicAdd(&cnt[d / SPAN], 1);
  }
  __syncthreads();
  int c = cnt[tid];
  blockBase[b * NB + tid] = c ? atomicAdd(&bucketCount[tid], c) : 0;
}

__global__ __launch_bounds__(512) void scanK(const int* __restrict__ bucketCount,
                                             int* __restrict__ bucketOffs) {
  __shared__ int sm[NB];
  const int t = threadIdx.x;
  int v = bucketCount[t];
  sm[t] = v;
  __syncthreads();
  for (int off = 1; off < NB; off <<= 1) {
    int u = (t >= off) ? sm[t - off] : 0;
    __syncthreads();
    sm[t] += u;
    __syncthreads();
  }
  bucketOffs[t] = sm[t] - v;         // exclusive
  if (t == NB - 1) bucketOffs[NB] = NE;
}

__global__ __launch_bounds__(512) void scatK(const int* __restrict__ ei,
                                             const int* __restrict__ bucketOffs,
                                             const int* __restrict__ blockBase,
                                             unsigned* __restrict__ pairs) {
  __shared__ int cur[NB];
  const int b = blockIdx.x, tid = threadIdx.x;
  cur[tid] = 0;
  __syncthreads();
  const int base = b * EPB;
  for (int e = tid; e < EPB; e += 512) {
    int s = ei[base + e];
    int d = ei[NE + base + e];
    int j = d / SPAN;
    int dl = d - j * SPAN;
    int r = atomicAdd(&cur[j], 1);
    pairs[bucketOffs[j] + blockBase[b * NB + j] + r] = (unsigned)s | ((unsigned)dl << 17);
  }
}

// ===========================================================================
// Layer-1 aggregate: one block per bucket, LDS accumulator [SPAN][16].
// 16 lanes per edge (col = tid&15) -> 64B coalesced gather of h0 row.
// ===========================================================================
__global__ __launch_bounds__(512) void agg16K(const int* __restrict__ bucketOffs,
                                              const unsigned* __restrict__ pairs,
                                              const float* __restrict__ h0,
                                              float* __restrict__ agg) {
  __shared__ float acc[SPAN * NH];   // 12544 B
  const int j = blockIdx.x, tid = threadIdx.x;
  for (int i = tid; i < SPAN * NH; i += 512) acc[i] = 0.f;
  __syncthreads();
  const int beg = bucketOffs[j], end = bucketOffs[j + 1];
  const int col = tid & 15, slot = tid >> 4;   // 32 edge slots
  int e = beg + slot;
  for (; e + 32 < end; e += 64) {              // 2x unrolled for MLP
    unsigned pk0 = pairs[e];
    unsigned pk1 = pairs[e + 32];
    float v0 = h0[(size_t)(pk0 & 0x1FFFF) * NH + col];
    float v1 = h0[(size_t)(pk1 & 0x1FFFF) * NH + col];
    atomicAdd(&acc[(pk0 >> 17) * NH + col], v0);
    atomicAdd(&acc[(pk1 >> 17) * NH + col], v1);
  }
  if (e < end) {
    unsigned pk = pairs[e];
    atomicAdd(&acc[(pk >> 17) * NH + col], h0[(size_t)(pk & 0x1FFFF) * NH + col]);
  }
  __syncthreads();
  const int lo = j * SPAN;
  for (int i = tid; i < SPAN * NH; i += 512) {
    int node = lo + (i >> 4);
    if (node < NN) agg[(size_t)node * NH + (i & 15)] = acc[i];
  }
}

// ---------------------------------------------------------------------------
// Per-node transform: p[n, 0:7] = relu(agg1[n] + b1) @ W2, p stride 8.
// ---------------------------------------------------------------------------
__global__ __launch_bounds__(256) void transform_kernel(const float* __restrict__ agg1,
                                                        const float* __restrict__ b1,
                                                        const float* __restrict__ W2,
                                                        float* __restrict__ p) {
  int n = blockIdx.x * blockDim.x + threadIdx.x;
  if (n >= NN) return;
  const float4* r = (const float4*)(agg1 + (size_t)n * NH);
  float4 v0 = r[0], v1 = r[1], v2 = r[2], v3 = r[3];
  float h[NH] = {v0.x, v0.y, v0.z, v0.w, v1.x, v1.y, v1.z, v1.w,
                 v2.x, v2.y, v2.z, v2.w, v3.x, v3.y, v3.z, v3.w};
#pragma unroll
  for (int k = 0; k < NH; ++k) h[k] = fmaxf(h[k] + b1[k], 0.f);

#pragma unroll
  for (int j = 0; j < NC; ++j) {
    float acc = 0.f;
#pragma unroll
    for (int k = 0; k < NH; ++k) acc += h[k] * W2[k * NC + j];
    p[(size_t)n * 8 + j] = acc;
  }
  p[(size_t)n * 8 + 7] = 0.f;   // pad col must be clean: agg8K accumulates it
}

// ===========================================================================
// Layer-2 aggregate: LDS accumulator [SPAN][8]; 8 lanes per edge.
// ===========================================================================
__global__ __launch_bounds__(512) void agg8K(const int* __restrict__ bucketOffs,
                                             const unsigned* __restrict__ pairs,
                                             const float* __restrict__ p,
                                             float* __restrict__ agg) {
  __shared__ float acc[SPAN * 8];    // 6272 B
  const int j = blockIdx.x, tid = threadIdx.x;
  for (int i = tid; i < SPAN * 8; i += 512) acc[i] = 0.f;
  __syncthreads();
  const int beg = bucketOffs[j], end = bucketOffs[j + 1];
  const int col = tid & 7, slot = tid >> 3;    // 64 edge slots
  int e = beg + slot;
  for (; e + 64 < end; e += 128) {             // 2x unrolled
    unsigned pk0 = pairs[e];
    unsigned pk1 = pairs[e + 64];
    float v0 = p[(size_t)(pk0 & 0x1FFFF) * 8 + col];
    float v1 = p[(size_t)(pk1 & 0x1FFFF) * 8 + col];
    atomicAdd(&acc[(pk0 >> 17) * 8 + col], v0);
    atomicAdd(&acc[(pk1 >> 17) * 8 + col], v1);
  }
  if (e < end) {
    unsigned pk = pairs[e];
    atomicAdd(&acc[(pk >> 17) * 8 + col], p[(size_t)(pk & 0x1FFFF) * 8 + col]);
  }
  __syncthreads();
  const int lo = j * SPAN;
  for (int i = tid; i < SPAN * 8; i += 512) {
    int node = lo + (i >> 3);
    if (node < NN) agg[(size_t)node * 8 + (i & 7)] = acc[i];
  }
}

// ---------------------------------------------------------------------------
// log_softmax over 7 classes; agg2 stride 8 in, out stride 7.
// ---------------------------------------------------------------------------
__global__ __launch_bounds__(256) void lsm_kernel(const float* __restrict__ agg2,
                                                  const float* __restrict__ b2,
                                                  float* __restrict__ out) {
  int n = blockIdx.x * blockDim.x + threadIdx.x;
  if (n >= NN) return;
  float z[NC];
  float m = -1e30f;
#pragma unroll
  for (int j = 0; j < NC; ++j) {
    z[j] = agg2[(size_t)n * 8 + j] + b2[j];
    m = fmaxf(m, z[j]);
  }
  float s = 0.f;
#pragma unroll
  for (int j = 0; j < NC; ++j) s += __expf(z[j] - m);
  float l = __logf(s);
#pragma unroll
  for (int j = 0; j < NC; ++j) out[(size_t)n * NC + j] = z[j] - m - l;
}

// ===========================================================================
// Legacy atomic-scatter path (fallback when workspace is too small).
// ===========================================================================
__global__ __launch_bounds__(256) void scatter16_kernel(const int* __restrict__ ei,
                                                        const float* __restrict__ h0,
                                                        float* __restrict__ agg) {
  long long gid = (long long)blockIdx.x * blockDim.x + threadIdx.x;
  int e = (int)(gid >> 4);
  if (e >= NE) return;
  int j = (int)(gid & 15);
  int s = ei[e];
  int d = ei[NE + e];
  atomicAdd(&agg[(size_t)d * NH + j], h0[(size_t)s * NH + j]);
}

__global__ __launch_bounds__(256) void scatter7_kernel(const int* __restrict__ ei,
                                                       const float* __restrict__ p,
                                                       float* __restrict__ agg) {
  long long gid = (long long)blockIdx.x * blockDim.x + threadIdx.x;
  int e = (int)(gid >> 3);
  if (e >= NE) return;
  int j = (int)(gid & 7);
  if (j >= NC) return;
  int s = ei[e];
  int d = ei[NE + e];
  atomicAdd(&agg[(size_t)d * 8 + j], p[(size_t)s * 8 + j]);
}

extern "C" void kernel_launch(void* const* d_in, const int* in_sizes, int n_in,
                              void* d_out, int out_size, void* d_ws, size_t ws_size,
                              hipStream_t stream) {
  const float* x  = (const float*)d_in[0];
  const int*   ei = (const int*)d_in[1];   // [2, NE] int32: src row then dst row
  const float* W1 = (const float*)d_in[2];
  const float* b1 = (const float*)d_in[3];
  const float* W2 = (const float*)d_in[4];
  const float* b2 = (const float*)d_in[5];
  float* out = (float*)d_out;

  // ws layout (25.6 MB):
  //   h0p   : NN*16 f32 (6.4 MB)  -- h0, later reused as p (stride 8)
  //   aggp  : NN*16 f32 (6.4 MB)  -- agg1 / agg2; first 512 KB aliases blockBase
  //   pairs : NE  u32 (12.8 MB)   -- bucket-ordered packed (src | dl<<17)
  //   bucketCount[NB], bucketOffs[NB+1]
  float*    h0p  = (float*)d_ws;
  float*    aggp = h0p + (size_t)NN * NH;
  unsigned* pairs = (unsigned*)(aggp + (size_t)NN * NH);
  int* bucketCount = (int*)(pairs + NE);
  int* bucketOffs  = bucketCount + NB;
  int* blockBase   = (int*)aggp;          // NBLK*NB ints = 512 KB, dead before agg16K
  size_t need = (size_t)((char*)(bucketOffs + NB + 1) - (char*)d_ws);

  if (ws_size >= need) {
    hipMemsetAsync(bucketCount, 0, NB * sizeof(int), stream);
    countK<<<NBLK, 512, 0, stream>>>(ei, bucketCount, blockBase);
    scanK<<<1, NB, 0, stream>>>(bucketCount, bucketOffs);
    scatK<<<NBLK, 512, 0, stream>>>(ei, bucketOffs, blockBase, pairs);

    gemm1_kernel<<<2048, 256, 0, stream>>>(x, W1, h0p);
    agg16K<<<NB, 512, 0, stream>>>(bucketOffs, pairs, h0p, aggp);
    transform_kernel<<<(NN + 255) / 256, 256, 0, stream>>>(aggp, b1, W2, h0p);
    agg8K<<<NB, 512, 0, stream>>>(bucketOffs, pairs, h0p, aggp);
    lsm_kernel<<<(NN + 255) / 256, 256, 0, stream>>>(aggp, b2, out);
  } else {
    // ---- legacy path (12.8 MB ws): verified at 705 us ----
    float* bufA = (float*)d_ws;
    float* bufB = bufA + (size_t)NN * NH;

    hipMemsetAsync(bufB, 0, (size_t)NN * NH * sizeof(float), stream);
    gemm1_kernel<<<2048, 256, 0, stream>>>(x, W1, bufA);
    scatter16_kernel<<<(int)(((long long)NE * 16 + 255) / 256), 256, 0, stream>>>(ei, bufA, bufB);
    transform_kernel<<<(NN + 255) / 256, 256, 0, stream>>>(bufB, b1, W2, bufA);
    hipMemsetAsync(bufB, 0, (size_t)NN * 8 * sizeof(float), stream);
    scatter7_kernel<<<(int)(((long long)NE * 8 + 255) / 256), 256, 0, stream>>>(ei, bufA, bufB);
    lsm_kernel<<<(NN + 255) / 256, 256, 0, stream>>>(bufB, b2, out);
  }
}